// Round 10
// baseline (575.832 us; speedup 1.0000x reference)
//
#include <hip/hip_runtime.h>
#include <hip/hip_bf16.h>

// B=8, S=2048, D=1024, fp32 in/out.
static constexpr int S = 2048;
static constexpr int D = 1024;
static constexpr int NB = 8;

#define LOG2E 1.4426950408889634f

typedef float  f32x4  __attribute__((ext_vector_type(4)));
typedef __bf16 bf16x4 __attribute__((ext_vector_type(4)));
typedef __bf16 bf16x8 __attribute__((ext_vector_type(8)));

#define CM_F32    0
#define CM_SPLIT  1
#define CM_TRANSV 2

#define GLD16(g, l) __builtin_amdgcn_global_load_lds(                         \
    (const __attribute__((address_space(1))) void*)(g),                       \
    (__attribute__((address_space(3))) void*)(l), 16, 0, 0)

#define MFMA16(a, b, c) __builtin_amdgcn_mfma_f32_16x16x32_bf16((a), (b), (c), 0, 0, 0)
#define BAR() __builtin_amdgcn_s_barrier()
#define PRIO1() __builtin_amdgcn_s_setprio(1)
#define PRIO0() __builtin_amdgcn_s_setprio(0)
#define WAIT_LGKM(n) asm volatile("s_waitcnt lgkmcnt(" #n ")" ::: "memory")
#define WAIT_VM(n)   asm volatile("s_waitcnt vmcnt(" #n ")" ::: "memory")

// ---------------------------------------------------------------------------
// 256xBNT tile, 8 waves, fine-phase K-loop with NEVER-DRAIN counted vmcnt.
// LDS per buffer = 4 k-plane regions (T3: {A-hi,A-lo,B-hi,B-lo}; T1: k-halves),
// each [rows][64 B], 4-slot XOR swizzle: LDS slot s of row r holds global
// chunk s^((r>>1)&3) (stage pre-swizzles the per-lane global chunk; read
// applies the same involution). 2 lanes/bank max -> conflict-free.
// Stage units = planes, issued {P0:A-hi, P1:B-hi, P2:A-lo, P3:B-lo} for tile
// t+1 during tile t -> every unit has >=4-phase lead. Seals (vmcnt+BAR, both
// block-wide): P1 vmcnt(2) retires t's lo planes; P5 vmcnt(4) retires t+1's
// hi planes. vmcnt(0) only in prologue / last tile. lgkmcnt fully counted;
// P5 lgkmcnt(0) BEFORE its barrier = block-wide read-drain (restage safety).
//   TERMS==3 (BNT=256): K-tile 32 real k, 6 MFMA phases (16 MFMA each):
//     M0 aA*b0  M1 aB*b0  M2 aA*b1  M3 aB*b1  M4 aA2*b0  M5 aB2*b0
//     (hi*hi, hi*lo, lo*hi split-bf16 fp32 emulation)
//   TERMS==1 (BNT=128): K-tile 64 k, 2 phases: M0 a0*b0, M1 a1*b1;
//     seals vmcnt(3) at P0 (retires t's k1) and P1 (retires t+1's k0).
// XCD-bijective block swizzle (T1/m204) kept (FETCH 135->49 MB, r8).
// ---------------------------------------------------------------------------
template <int TERMS, int CMODE, int BNT>
__global__ __launch_bounds__(512, 1) void bgemm256(
    const __bf16* __restrict__ Ah_, const __bf16* __restrict__ Al_, long sAz,
    const __bf16* __restrict__ Bh_, const __bf16* __restrict__ Bl_, long sBz,
    int lda, int ldb,
    void* __restrict__ C1, void* __restrict__ C2, int ldc, long sCz,
    const float* __restrict__ bias, int K)
{
    extern __shared__ char smem[];
    constexpr int NW_N  = BNT / 64;          // waves along N
    constexpr int NW_M  = 8 / NW_N;          // waves along M
    constexpr int WM    = 256 / NW_M;        // rows per wave tile
    constexpr int MI    = WM / 16;           // acc rows per wave
    constexpr int APLANE = 16384;            // 256 rows x 64 B
    constexpr int BPLANE = BNT * 64;         // BNT rows x 64 B
    constexpr int BOFF   = 2 * APLANE;
    constexpr int BUFSZ  = 2 * APLANE + 2 * BPLANE;

    // ---- XCD-aware bijective block swizzle (T1, m204) ----
    int bx, by, bz;
    {
        const int gx = gridDim.x, gy = gridDim.y;
        const int nwg = gx * gy * gridDim.z;
        const int wg = blockIdx.x + gx * (blockIdx.y + gy * blockIdx.z);
        const int q = nwg >> 3, r = nwg & 7;
        const int xcd = wg & 7, i = wg >> 3;
        const int nid = (xcd < r) ? xcd * (q + 1) + i
                                  : r * (q + 1) + (xcd - r) * q + i;
        bx = nid % gx;
        const int tmp = nid / gx;
        by = tmp % gy;
        bz = tmp / gy;
    }

    const int t = threadIdx.x;
    const int z = bz;
    const int m0 = by * 256;
    const int n0 = bx * BNT;
    const int lane = t & 63, wid = t >> 6;
    const int wr = wid / NW_N, wc = wid % NW_N;
    const int fr = lane & 15, fq = lane >> 4;
    const int lrow = lane >> 2, lslot = lane & 3;   // staging lane coords

    const __bf16* Ahz = Ah_ + (long)z * sAz;
    const __bf16* Alz = (TERMS == 3) ? Al_ + (long)z * sAz : nullptr;
    const __bf16* Bhz = Bh_ + (long)z * sBz;
    const __bf16* Blz = (TERMS == 3) ? Bl_ + (long)z * sBz : nullptr;

    // stage plane p of tile (T3: p=0 hi plane, p=1 lo plane; T1: k-half p)
    auto stA = [&](int tile, int p) {
        const __bf16* plane = (TERMS == 3 && p) ? Alz : Ahz;
        char* lbase = smem + (tile & 1) * BUFSZ + p * APLANE;
#pragma unroll
        for (int i = 0; i < 2; ++i) {
            const int row = wid * 32 + i * 16 + lrow;
            const int chunk = lslot ^ ((row >> 1) & 3);
            const long kk = (TERMS == 3) ? (long)tile * 32 + chunk * 8
                                         : (long)tile * 64 + p * 32 + chunk * 8;
            GLD16(plane + (long)(m0 + row) * lda + kk,
                  lbase + (wid * 32 + i * 16) * 64);
        }
    };
    auto stB = [&](int tile, int p) {
        const __bf16* plane = (TERMS == 3 && p) ? Blz : Bhz;
        char* lbase = smem + (tile & 1) * BUFSZ + BOFF + p * BPLANE;
        if (TERMS == 3) {
#pragma unroll
            for (int i = 0; i < 2; ++i) {
                const int row = wid * 32 + i * 16 + lrow;
                const int chunk = lslot ^ ((row >> 1) & 3);
                const long kk = (long)tile * 32 + chunk * 8;
                GLD16(plane + (long)(n0 + row) * ldb + kk,
                      lbase + (wid * 32 + i * 16) * 64);
            }
        } else {
            const int row = wid * 16 + lrow;
            const int chunk = lslot ^ ((row >> 1) & 3);
            const long kk = (long)tile * 64 + p * 32 + chunk * 8;
            GLD16(plane + (long)(n0 + row) * ldb + kk, lbase + (wid * 16) * 64);
        }
    };
    auto rdA = [&](int buf, int p, int c, int mi) -> bf16x8 {
        const int row = wr * WM + mi * 16 + fr;
        const int slot = c ^ ((row >> 1) & 3);
        return *(const bf16x8*)(smem + buf * BUFSZ + p * APLANE +
                                row * 64 + slot * 16);
    };
    auto rdB = [&](int buf, int p, int c, int ni) -> bf16x8 {
        const int row = wc * 64 + ni * 16 + fr;
        const int slot = c ^ ((row >> 1) & 3);
        return *(const bf16x8*)(smem + buf * BUFSZ + BOFF + p * BPLANE +
                                row * 64 + slot * 16);
    };

    f32x4 acc[MI][4] = {};
    const int ktiles = K / ((TERMS == 3) ? 32 : 64);

    if constexpr (TERMS == 3) {
        bf16x8 b0[4], b1[4], aA[4], aB[4], aA2[4], aB2[4];
        auto mb = [&](int base, bf16x8 (&A)[4], bf16x8 (&B)[4]) {
#pragma unroll
            for (int mi = 0; mi < 4; ++mi)
#pragma unroll
                for (int ni = 0; ni < 4; ++ni)
                    acc[base + mi][ni] = MFMA16(A[mi], B[ni], acc[base + mi][ni]);
        };
        // prologue: stage tile 0 fully; drain once; pre-read hi fragments
        stA(0, 0); stB(0, 0); stA(0, 1); stB(0, 1);
        WAIT_VM(0);
        BAR();
#pragma unroll
        for (int ni = 0; ni < 4; ++ni) b0[ni] = rdB(0, 0, fq, ni);
#pragma unroll
        for (int mi = 0; mi < 4; ++mi) aA[mi] = rdA(0, 0, fq, mi);
#pragma unroll
        for (int mi = 0; mi < 4; ++mi) aB[mi] = rdA(0, 0, fq, 4 + mi);

        for (int tt = 0; tt < ktiles; ++tt) {
            const int buf = tt & 1;
            const bool pf = (tt + 1 < ktiles);
            // ---- P0: M0 = aA·b0 ----
            if (pf) stA(tt + 1, 0);                       // A-hi(t+1)
            BAR();
            WAIT_LGKM(4);                                 // b0,aA landed (aB left)
            PRIO1(); mb(0, aA, b0); PRIO0();
            BAR();
            // ---- P1: seal lo(t); read b1; M1 = aB·b0 ----
            if (pf) { WAIT_VM(2); stB(tt + 1, 0); }       // retire A-lo,B-lo(t)
            else    { WAIT_VM(0); }
            BAR();                                        // lo planes sealed
#pragma unroll
            for (int ni = 0; ni < 4; ++ni) b1[ni] = rdB(buf, 1, fq, ni);
            WAIT_LGKM(4);                                 // aB landed (b1 left)
            PRIO1(); mb(4, aB, b0); PRIO0();
            BAR();
            // ---- P2: read aA2; M2 = aA·b1 ----
#pragma unroll
            for (int mi = 0; mi < 4; ++mi) aA2[mi] = rdA(buf, 1, fq, mi);
            if (pf) stA(tt + 1, 1);                       // A-lo(t+1)
            BAR();
            WAIT_LGKM(4);                                 // b1 landed (aA2 left)
            PRIO1(); mb(0, aA, b1); PRIO0();
            BAR();
            // ---- P3: read aB2; M3 = aB·b1 ----
#pragma unroll
            for (int mi = 0; mi < 4; ++mi) aB2[mi] = rdA(buf, 1, fq, 4 + mi);
            if (pf) stB(tt + 1, 1);                       // B-lo(t+1)
            BAR();
            PRIO1(); mb(4, aB, b1); PRIO0();
            BAR();
            // ---- P4: M4 = aA2·b0 ----
            WAIT_LGKM(4);                                 // aA2 landed (aB2 left)
            PRIO1(); mb(0, aA2, b0); PRIO0();
            BAR();
            // ---- P5: seal hi(t+1) + read-drain; M5 = aB2·b0; tail pre-reads ----
            if (pf) WAIT_VM(4);                           // retire A-hi,B-hi(t+1)
            WAIT_LGKM(0);                                 // all ds_reads drained
            BAR();                                        // block-wide seals
            PRIO1(); mb(4, aB2, b0); PRIO0();
            if (pf) {
                const int nb = buf ^ 1;
#pragma unroll
                for (int ni = 0; ni < 4; ++ni) b0[ni] = rdB(nb, 0, fq, ni);
#pragma unroll
                for (int mi = 0; mi < 4; ++mi) aA[mi] = rdA(nb, 0, fq, mi);
#pragma unroll
                for (int mi = 0; mi < 4; ++mi) aB[mi] = rdA(nb, 0, fq, 4 + mi);
            }
        }
    } else {  // TERMS == 1 (PV, BNT=128, MI=4)
        bf16x8 b0[4], b1[4], a0[4], a1[4];
        auto mb = [&](bf16x8 (&A)[4], bf16x8 (&B)[4]) {
#pragma unroll
            for (int mi = 0; mi < 4; ++mi)
#pragma unroll
                for (int ni = 0; ni < 4; ++ni)
                    acc[mi][ni] = MFMA16(A[mi], B[ni], acc[mi][ni]);
        };
        stA(0, 0); stB(0, 0); stA(0, 1); stB(0, 1);
        WAIT_VM(0);
        BAR();
#pragma unroll
        for (int ni = 0; ni < 4; ++ni) b0[ni] = rdB(0, 0, fq, ni);
#pragma unroll
        for (int mi = 0; mi < 4; ++mi) a0[mi] = rdA(0, 0, fq, mi);

        for (int tt = 0; tt < ktiles; ++tt) {
            const int buf = tt & 1;
            const bool pf = (tt + 1 < ktiles);
            // ---- P0: seal k1(t); read k1 frags; M0 = a0·b0 ----
            if (pf) { stA(tt + 1, 0); stB(tt + 1, 0); WAIT_VM(3); }
            else    { WAIT_VM(0); }
            BAR();                                        // k1(t) sealed
#pragma unroll
            for (int ni = 0; ni < 4; ++ni) b1[ni] = rdB(buf, 1, fq, ni);
#pragma unroll
            for (int mi = 0; mi < 4; ++mi) a1[mi] = rdA(buf, 1, fq, mi);
            WAIT_LGKM(8);                                 // b0,a0 landed
            PRIO1(); mb(a0, b0); PRIO0();
            BAR();
            // ---- P1: seal k0(t+1) + read-drain; M1 = a1·b1; tail ----
            if (pf) { stA(tt + 1, 1); stB(tt + 1, 1); WAIT_VM(3); }
            WAIT_LGKM(0);
            BAR();
            PRIO1(); mb(a1, b1); PRIO0();
            if (pf) {
                const int nb = buf ^ 1;
#pragma unroll
                for (int ni = 0; ni < 4; ++ni) b0[ni] = rdB(nb, 0, fq, ni);
#pragma unroll
                for (int mi = 0; mi < 4; ++mi) a0[mi] = rdA(nb, 0, fq, mi);
            }
        }
    }

    // ---------------- epilogue ----------------
#pragma unroll
    for (int mi = 0; mi < MI; ++mi) {
        const int rbase = m0 + wr * WM + mi * 16 + fq * 4;
#pragma unroll
        for (int ni = 0; ni < 4; ++ni) {
            const int col = n0 + wc * 64 + ni * 16 + fr;
            f32x4 a = acc[mi][ni];
            if (CMODE != CM_F32) {
                const float bv = bias[col];
#pragma unroll
                for (int j = 0; j < 4; ++j) a[j] += bv;
            }
            if (CMODE == CM_F32) {
                float* C = (float*)C1 + (long)z * sCz;
#pragma unroll
                for (int j = 0; j < 4; ++j)
                    C[(long)(rbase + j) * ldc + col] = a[j];
            } else if (CMODE == CM_SPLIT) {
                __bf16* Ch = (__bf16*)C1;
                __bf16* Cl = (__bf16*)C2;
#pragma unroll
                for (int j = 0; j < 4; ++j) {
                    const float q = a[j];
                    const __bf16 h = (__bf16)q;
                    Ch[(long)(rbase + j) * ldc + col] = h;
                    Cl[(long)(rbase + j) * ldc + col] = (__bf16)(q - (float)h);
                }
            } else {  // CM_TRANSV: Vt[b][col][s] bf16
                const int b_ = rbase >> 11;
                const int s_ = rbase & (S - 1);
                bf16x4 h;
#pragma unroll
                for (int j = 0; j < 4; ++j) h[j] = (__bf16)a[j];
                *(bf16x4*)((__bf16*)C1 + ((long)b_ * D + col) * S + s_) = h;
            }
        }
    }
}

// ---------------------------------------------------------------------------
__global__ __launch_bounds__(256) void xsplit(
    const float* __restrict__ X, __bf16* __restrict__ Xh, __bf16* __restrict__ Xl)
{
    const long i = ((long)blockIdx.x * 256 + threadIdx.x) * 4;
    f32x4 v = *(const f32x4*)(X + i);
    bf16x4 h, l;
#pragma unroll
    for (int j = 0; j < 4; ++j) {
        h[j] = (__bf16)v[j];
        l[j] = (__bf16)(v[j] - (float)h[j]);
    }
    *(bf16x4*)(Xh + i) = h;
    *(bf16x4*)(Xl + i) = l;
}

// ---------------------------------------------------------------------------
__global__ void wsplit(const float* __restrict__ W0, const float* __restrict__ W1,
                       const float* __restrict__ W2,
                       __bf16* __restrict__ Th, __bf16* __restrict__ Tl)
{
    const float* W = blockIdx.z == 0 ? W0 : (blockIdx.z == 1 ? W1 : W2);
    __bf16* th = Th + (long)blockIdx.z * 1024 * 1024;
    __bf16* tl = Tl + (long)blockIdx.z * 1024 * 1024;
    __shared__ float tile[32][33];
    const int bx = blockIdx.x * 32, by = blockIdx.y * 32;
    const int tx = threadIdx.x, ty = threadIdx.y;
#pragma unroll
    for (int i = ty; i < 32; i += 8) tile[i][tx] = W[(long)(by + i) * 1024 + bx + tx];
    __syncthreads();
#pragma unroll
    for (int i = ty; i < 32; i += 8) {
        const float v = tile[tx][i];
        const __bf16 h = (__bf16)v;
        th[(long)(bx + i) * 1024 + by + tx] = h;
        tl[(long)(bx + i) * 1024 + by + tx] = (__bf16)(v - (float)h);
    }
}

// ---------------------------------------------------------------------------
// Fused row softmax: read f32 score row, write P = exp(s-m)/l as bf16
// IN-PLACE into the start of the row's f32 storage.
// ---------------------------------------------------------------------------
__global__ __launch_bounds__(256) void pconv(float* __restrict__ Sb)
{
    const long row = blockIdx.x;
    float* p = Sb + row * (long)S;
    const int t = threadIdx.x;

    f32x4 x0 = *(const f32x4*)(p + t * 8);
    f32x4 x1 = *(const f32x4*)(p + t * 8 + 4);

    float m = -3.4e38f;
#pragma unroll
    for (int j = 0; j < 4; ++j) m = fmaxf(m, fmaxf(x0[j], x1[j]));
#pragma unroll
    for (int o = 32; o >= 1; o >>= 1) m = fmaxf(m, __shfl_xor(m, o));

    __shared__ float wm[4], wsum[4];
    const int wid = t >> 6, lane = t & 63;
    if (lane == 0) wm[wid] = m;
    __syncthreads();
    m = fmaxf(fmaxf(wm[0], wm[1]), fmaxf(wm[2], wm[3]));

    float e[8], ssum = 0.f;
#pragma unroll
    for (int j = 0; j < 4; ++j) {
        e[j]     = exp2f((x0[j] - m) * LOG2E);
        e[4 + j] = exp2f((x1[j] - m) * LOG2E);
        ssum += e[j] + e[4 + j];
    }
#pragma unroll
    for (int o = 32; o >= 1; o >>= 1) ssum += __shfl_xor(ssum, o);
    if (lane == 0) wsum[wid] = ssum;
    __syncthreads();
    const float invl = 1.0f / (wsum[0] + wsum[1] + wsum[2] + wsum[3]);

    bf16x8 outv;
#pragma unroll
    for (int j = 0; j < 8; ++j) outv[j] = (__bf16)(e[j] * invl);
    *(bf16x8*)((__bf16*)p + t * 8) = outv;
}

// ---------------------------------------------------------------------------
extern "C" void kernel_launch(void* const* d_in, const int* in_sizes, int n_in,
                              void* d_out, int out_size, void* d_ws, size_t ws_size,
                              hipStream_t stream)
{
    const float* X  = (const float*)d_in[0];
    const float* Wq = (const float*)d_in[1];
    const float* bq = (const float*)d_in[2];
    const float* Wk = (const float*)d_in[3];
    const float* bk = (const float*)d_in[4];
    const float* Wv = (const float*)d_in[5];
    const float* bv = (const float*)d_in[6];
    float* out = (float*)d_out;
    char* ws = (char*)d_ws;
    const size_t MB = 1u << 20;

    // layout (236 MB):
    // [0,6) Wth[3]  [6,12) Wtl[3]
    // [12,76) X region: Xh|Xl during projections; Sb f32 [4][S][S] after (P in-place)
    // [76,108) Qh  [108,140) Ql  [140,172) Kh  [172,204) Kl  [204,236) Vt bf16
    __bf16* Wth = (__bf16*)ws;          __bf16* Wtl = (__bf16*)(ws + 6 * MB);
    __bf16* Xh = (__bf16*)(ws + 12 * MB);  __bf16* Xl = (__bf16*)(ws + 44 * MB);
    __bf16* Qh = (__bf16*)(ws + 76 * MB);  __bf16* Ql = (__bf16*)(ws + 108 * MB);
    __bf16* Kh = (__bf16*)(ws + 140 * MB); __bf16* Kl = (__bf16*)(ws + 172 * MB);
    __bf16* Vt = (__bf16*)(ws + 204 * MB);
    float*  Sb = (float*)(ws + 12 * MB);   // [4][S][S] f32; P bf16 in-place

    const int LDS_T3 = 131072;             // 2 bufs x (2x16K A + 2x16K B)
    const int LDS_T1 = 98304;              // 2 bufs x (2x16K A + 2x8K B)
    hipFuncSetAttribute(reinterpret_cast<const void*>(&bgemm256<3, CM_SPLIT, 256>),
                        hipFuncAttributeMaxDynamicSharedMemorySize, LDS_T3);
    hipFuncSetAttribute(reinterpret_cast<const void*>(&bgemm256<3, CM_TRANSV, 256>),
                        hipFuncAttributeMaxDynamicSharedMemorySize, LDS_T3);
    hipFuncSetAttribute(reinterpret_cast<const void*>(&bgemm256<3, CM_F32, 256>),
                        hipFuncAttributeMaxDynamicSharedMemorySize, LDS_T3);
    hipFuncSetAttribute(reinterpret_cast<const void*>(&bgemm256<1, CM_F32, 128>),
                        hipFuncAttributeMaxDynamicSharedMemorySize, LDS_T1);

    // 1) split inputs to bf16 hi/lo planes
    xsplit<<<dim3(16384), 256, 0, stream>>>(X, Xh, Xl);
    wsplit<<<dim3(32, 32, 3), dim3(32, 8), 0, stream>>>(Wq, Wk, Wv, Wth, Wtl);

    // 2) projections (3-term split GEMM)
    const long MW = 1024 * 1024;
    bgemm256<3, CM_SPLIT, 256><<<dim3(D / 256, 64, 1), 512, LDS_T3, stream>>>(
        Xh, Xl, 0, Wth, Wtl, 0, D, D, Qh, Ql, D, 0, bq, D);
    bgemm256<3, CM_SPLIT, 256><<<dim3(D / 256, 64, 1), 512, LDS_T3, stream>>>(
        Xh, Xl, 0, Wth + MW, Wtl + MW, 0, D, D, Kh, Kl, D, 0, bk, D);
    bgemm256<3, CM_TRANSV, 256><<<dim3(D / 256, 64, 1), 512, LDS_T3, stream>>>(
        Xh, Xl, 0, Wth + 2 * MW, Wtl + 2 * MW, 0, D, D, Vt, nullptr, 0, 0, bv, D);

    // 3) per 4-batch group: scores -> in-place softmax->bf16 P -> PV
    for (int g = 0; g < 2; ++g) {
        const int b0 = g * 4;
        bgemm256<3, CM_F32, 256><<<dim3(S / 256, S / 256, 4), 512, LDS_T3, stream>>>(
            Qh + (long)b0 * S * D, Ql + (long)b0 * S * D, (long)S * D,
            Kh + (long)b0 * S * D, Kl + (long)b0 * S * D, (long)S * D,
            D, D, Sb, nullptr, S, (long)S * S, nullptr, D);
        pconv<<<dim3(4 * S), 256, 0, stream>>>(Sb);
        // PV: A = bf16 P rows embedded in f32 buffer (lda = 2S bf16 elements)
        bgemm256<1, CM_F32, 128><<<dim3(D / 128, S / 256, 4), 512, LDS_T1, stream>>>(
            (const __bf16*)Sb, nullptr, 2L * S * S,
            Vt + (long)b0 * D * S, nullptr, (long)D * S,
            2 * S, S, out + (long)b0 * S * D, nullptr, D, (long)S * D, nullptr, S);
    }
}